// Round 1
// baseline (253.758 us; speedup 1.0000x reference)
//
// PointNet++ FP: three_nn + three_interpolate + pointwise MLP(384->256->128)
// Round 9: occupancy-first restructure. r8 counters: Occupancy 23.7%, VALU 41%,
// Mfma 4.3%, HBM 6% -> latency-bound, nothing saturated. Changes:
//  * 32-point blocks (2048 blocks, 8/CU assigned vs 4). Wave OWNS its 8 points:
//    lane = (chunk<<3)|point, 256 candidates/lane in 4 ILP chains; top-3 merge
//    is a 3-step shfl_xor butterfly (index-ordered => tie-safe). No LDS scratch,
//    no cross-wave merge, NO barriers from scan through gather.
//  * LDS 51.7KB -> 16KB: Xs/Y1 = [32][256] bf16, XOR-swizzled (byte ^=
//    (row&7)<<4, T2) instead of padded -> conflict-free ds_read_b128.
//  * skip features (points1) skip LDS entirely: layer-1 kk=8..11 loads
//    A-fragments straight from global in MFMA layout (f32->bf16 cvt).
//  * weights/indices broadcast per-point via __shfl (iw LDS gone).
// 3 barriers total (gather->L1, L1-reads->Y1 overlay, Y1->L2).
// MFMA 16x16x32 bf16 layouts (learn_hip m89/m120 verified):
//   A: [m=lane&15][k=(lane>>4)*8+j]   B: [k=(lane>>4)*8+j][n=lane&15]
//   D: [row=(lane>>4)*4+reg][col=lane&15]
#include <hip/hip_runtime.h>

typedef __bf16 bf16_t;
typedef bf16_t bf16x4_t __attribute__((ext_vector_type(4)));
typedef bf16_t bf16x8_t __attribute__((ext_vector_type(8)));
typedef float floatx4_t __attribute__((ext_vector_type(4)));

constexpr int B_ = 8, N_ = 8192, M_ = 2048;
constexpr int C1 = 128, C2 = 256;
constexpr int K1 = 384, N1 = 256, N2 = 128;

// ws layout (bytes) -- unchanged from r8
constexpr size_t WS_W1T   = 0;         // bf16  [256][384]  = 196608 B
constexpr size_t WS_W2T   = 196608;    // bf16  [128][256]  =  65536 B
constexpr size_t WS_XYZ2P = 262144;    // float4[8*2048]    = 262144 B

// ---------------------------------------------------------------- prep ----
__global__ __launch_bounds__(256) void prep_kernel(
    const float* __restrict__ W1, const float* __restrict__ W2,
    const float* __restrict__ xyz2,
    bf16_t* __restrict__ W1T, bf16_t* __restrict__ W2T,
    float4* __restrict__ xyz2p) {
  int bid = blockIdx.x, tid = threadIdx.x;
  if (bid < 384) {                       // W1 [384][256] -> W1T [256][384]
    int t = bid * 256 + tid;             // 98304 elems
    int n = t / K1, k = t - n * K1;
    W1T[t] = (bf16_t)W1[k * N1 + n];
  } else if (bid < 512) {                // W2 [256][128] -> W2T [128][256]
    int t = (bid - 384) * 256 + tid;     // 32768 elems
    int n = t / N1, k = t - n * N1;
    W2T[t] = (bf16_t)W2[k * N2 + n];
  } else {                               // xyz2 -> float4{x,y,z,|q|^2}
    int t = (bid - 512) * 256 + tid;     // 16384 elems
    const float* p = xyz2 + (size_t)t * 3;
    float x = p[0], y = p[1], z = p[2];
    xyz2p[t] = make_float4(x, y, z, x * x + y * y + z * z);
  }
}

// ---------------------------------------------- fused nn+interp+MLP -------
// 2048 blocks x 256 threads; block owns 32 points of batch b = bi&7 (XCD-local
// points2/xyz2p slices). Wave w owns points w*8..w*8+7 end-to-end.
__global__ __launch_bounds__(256, 5) void fp_fused_kernel(
    const float* __restrict__ xyz1, const float4* __restrict__ xyz2p,
    const float* __restrict__ points1, const float* __restrict__ points2,
    const bf16_t* __restrict__ W1T, const float* __restrict__ b1,
    const bf16_t* __restrict__ W2T, const float* __restrict__ b2,
    float* __restrict__ out) {
  // Xs (interp, gather phase) then Y1 (layer-2 A) overlay: [32][256] bf16,
  // XOR-swizzled: byte_in_row ^= (row&7)<<4  (16B-granular, bijective)
  __shared__ __align__(16) char smem[32 * 512];   // 16384 B

  int bi = blockIdx.x;
  int b = bi & 7;                  // batch -> XCD (round-robin)
  int base = (bi >> 3) * 32;       // tile within batch (0..255)
  int tid = threadIdx.x;
  int wave = __builtin_amdgcn_readfirstlane(tid >> 6);  // 0..3
  int lane = tid & 63;
  size_t bN = (size_t)b * N_ + base;

  float w0, w1, w2;                // blend weights (all lanes, own point)
  int   i0, i1, i2;                // top-3 indices  (all lanes, own point)

  // ============ Phase S: three_nn, wave-private (NO barriers) =============
  {
    int pi = lane & 7;             // point within wave's 8
    int c  = lane >> 3;            // candidate chunk 0..7 (256 cand each)
    const float* p1 = xyz1 + (bN + wave * 8 + pi) * 3;
    float x = p1[0], y = p1[1], z = p1[2];
    float sq1 = x * x + y * y + z * z;
    float m2x = -2.0f * x, m2y = -2.0f * y, m2z = -2.0f * z;

    const float4* p2 = xyz2p + b * M_ + (c << 8);
    int jb = c << 8;               // global candidate base for this lane

    float cd0[4], cd1[4], cd2[4];
    int   ci0[4], ci1[4], ci2[4];
#pragma unroll
    for (int t = 0; t < 4; ++t) {
      cd0[t] = 1e30f; cd1[t] = 1e30f; cd2[t] = 1e30f;
      ci0[t] = 0; ci1[t] = 0; ci2[t] = 0;
    }
    // top-3 insert on d_rel = d2 - sq1 (per-point constant shift: same argmin)
    auto proc = [&](const float4& qv, int jj, int tc) {
      float d = fmaf(m2x, qv.x, fmaf(m2y, qv.y, fmaf(m2z, qv.z, qv.w)));
      bool l0 = d < cd0[tc], l1 = d < cd1[tc], l2 = d < cd2[tc];
      float n0v = fminf(cd0[tc], d);
      float n1v = __builtin_amdgcn_fmed3f(d, cd0[tc], cd1[tc]);
      float n2v = __builtin_amdgcn_fmed3f(d, cd1[tc], cd2[tc]);
      int t1 = l0 ? ci0[tc] : jj;
      int t2 = l1 ? ci1[tc] : jj;
      ci0[tc] = l0 ? jj : ci0[tc];
      ci1[tc] = l1 ? t1 : ci1[tc];
      ci2[tc] = l2 ? t2 : ci2[tc];
      cd0[tc] = n0v; cd1[tc] = n1v; cd2[tc] = n2v;
    };

    float4 bA[4], bB[4];
#pragma unroll
    for (int t = 0; t < 4; ++t) bA[t] = p2[t];
    for (int j = 0; j < 256; j += 8) {
#pragma unroll
      for (int t = 0; t < 4; ++t) bB[t] = p2[j + 4 + t];
#pragma unroll
      for (int t = 0; t < 4; ++t) proc(bA[t], jb + j + t, t);
      if (j + 8 < 256) {
#pragma unroll
        for (int t = 0; t < 4; ++t) bA[t] = p2[j + 8 + t];
      }
#pragma unroll
      for (int t = 0; t < 4; ++t) proc(bB[t], jb + j + 4 + t, t);
    }

    // in-lane merge of the 4 chains -> sorted (s0<=s1<=s2)
    float s0 = cd0[0], s1 = cd1[0], s2 = cd2[0];
    int   a0 = ci0[0], a1 = ci1[0], a2 = ci2[0];
    auto ins = [&](float d, int j) {
      if (d < s2) {
        if (d < s1) {
          s2 = s1; i2_swap: ;
          a2 = a1;
          if (d < s0) { s1 = s0; a1 = a0; s0 = d; a0 = j; }
          else        { s1 = d;  a1 = j; }
        } else { s2 = d; a2 = j; }
      }
    };
#pragma unroll
    for (int t = 1; t < 4; ++t) {
      ins(cd0[t], ci0[t]); ins(cd1[t], ci1[t]); ins(cd2[t], ci2[t]);
    }

    // butterfly merge across the 8 chunk-lanes of this point (bits 3,4,5).
    // Always merge (low-chunk list) <- insert (high-chunk list): chunk order
    // == index order, strict < keeps lower index on ties (matches top_k).
    auto xmerge = [&](int mb) {
      float o0 = __shfl_xor(s0, mb), o1 = __shfl_xor(s1, mb), o2 = __shfl_xor(s2, mb);
      int   p0 = __shfl_xor(a0, mb), p1i = __shfl_xor(a1, mb), p2i = __shfl_xor(a2, mb);
      bool hi = (lane & mb) != 0;
      float h0 = hi ? s0 : o0, h1 = hi ? s1 : o1, h2 = hi ? s2 : o2;
      int   g0 = hi ? a0 : p0, g1 = hi ? a1 : p1i, g2 = hi ? a2 : p2i;
      if (hi) { s0 = o0; s1 = o1; s2 = o2; a0 = p0; a1 = p1i; a2 = p2i; }
      ins(h0, g0); ins(h1, g1); ins(h2, g2);
    };
    xmerge(8); xmerge(16); xmerge(32);
    // now every lane holds the final top-3 of its point pi

    float e0 = fmaxf(s0 + sq1, 1e-10f);
    float e1 = fmaxf(s1 + sq1, 1e-10f);
    float e2 = fmaxf(s2 + sq1, 1e-10f);
    float r0 = 1.0f / e0, r1 = 1.0f / e1, r2 = 1.0f / e2;
    float rs = 1.0f / (r0 + r1 + r2);
    w0 = r0 * rs; w1 = r1 * rs; w2 = r2 * rs;
    i0 = a0; i1 = a1; i2 = a2;
  }

  // ============ Phase A: gather -> Xs[32][256] bf16 (swizzled) ============
  // wave w fills rows w*8..w*8+7; per-point params broadcast via shfl from
  // lane i (holds point pi=i for i<8). No barrier needed before this.
#pragma unroll 2
  for (int i = 0; i < 8; ++i) {
    int j0 = __shfl(i0, i), j1 = __shfl(i1, i), j2 = __shfl(i2, i);
    float u0 = __shfl(w0, i), u1 = __shfl(w1, i), u2 = __shfl(w2, i);
    const float* g0 = points2 + (size_t)(b * M_ + j0) * C2 + lane * 4;
    const float* g1 = points2 + (size_t)(b * M_ + j1) * C2 + lane * 4;
    const float* g2 = points2 + (size_t)(b * M_ + j2) * C2 + lane * 4;
    float4 a0 = *(const float4*)g0;
    float4 a1 = *(const float4*)g1;
    float4 a2 = *(const float4*)g2;
    bf16x4_t v;
    v[0] = (bf16_t)(u0 * a0.x + u1 * a1.x + u2 * a2.x);
    v[1] = (bf16_t)(u0 * a0.y + u1 * a1.y + u2 * a2.y);
    v[2] = (bf16_t)(u0 * a0.z + u1 * a1.z + u2 * a2.z);
    v[3] = (bf16_t)(u0 * a0.w + u1 * a1.w + u2 * a2.w);
    int p = wave * 8 + i;
    int off = (p << 9) + ((lane * 8) ^ (i << 4));   // (p&7)==i for i<8
    *(bf16x4_t*)(smem + off) = v;
  }
  __syncthreads();

  int q = lane >> 4, r = lane & 15;
  int rs8 = (r & 7) << 4;              // row-swizzle XOR (rows r and 16+r: same)

  // ---- Layer 1: [32 x 384] x [384 x 256], wave owns 64 output cols
  floatx4_t acc[2][4] = {};
  const bf16_t* wq0 = W1T + (size_t)(wave * 64 +  0 + r) * K1;
  const bf16_t* wq1 = W1T + (size_t)(wave * 64 + 16 + r) * K1;
  const bf16_t* wq2 = W1T + (size_t)(wave * 64 + 32 + r) * K1;
  const bf16_t* wq3 = W1T + (size_t)(wave * 64 + 48 + r) * K1;

  // interp part: K = 0..255 from LDS
  for (int kk = 0; kk < 8; ++kk) {
    int k0 = kk * 32 + q * 8;
    int co = (k0 << 1) ^ rs8;
    bf16x8_t a0 = *(const bf16x8_t*)(smem + ((     r) << 9) + co);
    bf16x8_t a1 = *(const bf16x8_t*)(smem + ((16 + r) << 9) + co);
    bf16x8_t bb0 = *(const bf16x8_t*)(wq0 + k0);
    bf16x8_t bb1 = *(const bf16x8_t*)(wq1 + k0);
    bf16x8_t bb2 = *(const bf16x8_t*)(wq2 + k0);
    bf16x8_t bb3 = *(const bf16x8_t*)(wq3 + k0);
    acc[0][0] = __builtin_amdgcn_mfma_f32_16x16x32_bf16(a0, bb0, acc[0][0], 0, 0, 0);
    acc[1][0] = __builtin_amdgcn_mfma_f32_16x16x32_bf16(a1, bb0, acc[1][0], 0, 0, 0);
    acc[0][1] = __builtin_amdgcn_mfma_f32_16x16x32_bf16(a0, bb1, acc[0][1], 0, 0, 0);
    acc[1][1] = __builtin_amdgcn_mfma_f32_16x16x32_bf16(a1, bb1, acc[1][1], 0, 0, 0);
    acc[0][2] = __builtin_amdgcn_mfma_f32_16x16x32_bf16(a0, bb2, acc[0][2], 0, 0, 0);
    acc[1][2] = __builtin_amdgcn_mfma_f32_16x16x32_bf16(a1, bb2, acc[1][2], 0, 0, 0);
    acc[0][3] = __builtin_amdgcn_mfma_f32_16x16x32_bf16(a0, bb3, acc[0][3], 0, 0, 0);
    acc[1][3] = __builtin_amdgcn_mfma_f32_16x16x32_bf16(a1, bb3, acc[1][3], 0, 0, 0);
  }
  // skip part: K = 256..383, A-fragments straight from points1 (no LDS)
#pragma unroll
  for (int kk = 0; kk < 4; ++kk) {
    int cc0 = kk * 32 + q * 8;
    const float* sp0 = points1 + (bN +      r) * (size_t)C1 + cc0;
    const float* sp1 = points1 + (bN + 16 + r) * (size_t)C1 + cc0;
    float4 f00 = *(const float4*)sp0, f01 = *(const float4*)(sp0 + 4);
    float4 f10 = *(const float4*)sp1, f11 = *(const float4*)(sp1 + 4);
    bf16x8_t a0, a1;
    a0[0] = (bf16_t)f00.x; a0[1] = (bf16_t)f00.y; a0[2] = (bf16_t)f00.z; a0[3] = (bf16_t)f00.w;
    a0[4] = (bf16_t)f01.x; a0[5] = (bf16_t)f01.y; a0[6] = (bf16_t)f01.z; a0[7] = (bf16_t)f01.w;
    a1[0] = (bf16_t)f10.x; a1[1] = (bf16_t)f10.y; a1[2] = (bf16_t)f10.z; a1[3] = (bf16_t)f10.w;
    a1[4] = (bf16_t)f11.x; a1[5] = (bf16_t)f11.y; a1[6] = (bf16_t)f11.z; a1[7] = (bf16_t)f11.w;
    int k0 = 256 + cc0;
    bf16x8_t bb0 = *(const bf16x8_t*)(wq0 + k0);
    bf16x8_t bb1 = *(const bf16x8_t*)(wq1 + k0);
    bf16x8_t bb2 = *(const bf16x8_t*)(wq2 + k0);
    bf16x8_t bb3 = *(const bf16x8_t*)(wq3 + k0);
    acc[0][0] = __builtin_amdgcn_mfma_f32_16x16x32_bf16(a0, bb0, acc[0][0], 0, 0, 0);
    acc[1][0] = __builtin_amdgcn_mfma_f32_16x16x32_bf16(a1, bb0, acc[1][0], 0, 0, 0);
    acc[0][1] = __builtin_amdgcn_mfma_f32_16x16x32_bf16(a0, bb1, acc[0][1], 0, 0, 0);
    acc[1][1] = __builtin_amdgcn_mfma_f32_16x16x32_bf16(a1, bb1, acc[1][1], 0, 0, 0);
    acc[0][2] = __builtin_amdgcn_mfma_f32_16x16x32_bf16(a0, bb2, acc[0][2], 0, 0, 0);
    acc[1][2] = __builtin_amdgcn_mfma_f32_16x16x32_bf16(a1, bb2, acc[1][2], 0, 0, 0);
    acc[0][3] = __builtin_amdgcn_mfma_f32_16x16x32_bf16(a0, bb3, acc[0][3], 0, 0, 0);
    acc[1][3] = __builtin_amdgcn_mfma_f32_16x16x32_bf16(a1, bb3, acc[1][3], 0, 0, 0);
  }
  __syncthreads();   // Xs dead only when ALL waves finished layer-1 LDS reads

  // bias + relu -> Y1 (bf16, overlays Xs, same swizzle)
#pragma unroll
  for (int mt = 0; mt < 2; ++mt) {
#pragma unroll
    for (int ct = 0; ct < 4; ++ct) {
      int nn = wave * 64 + ct * 16 + r;
      float bias = b1[nn];
#pragma unroll
      for (int reg = 0; reg < 4; ++reg) {
        int m = mt * 16 + q * 4 + reg;
        int off = (m << 9) + ((nn << 1) ^ ((m & 7) << 4));
        *(bf16_t*)(smem + off) = (bf16_t)fmaxf(acc[mt][ct][reg] + bias, 0.0f);
      }
    }
  }
  __syncthreads();

  // ---- Layer 2: [32 x 256] x [256 x 128] -> out, wave owns 32 cols
  floatx4_t acc2[2][2] = {};
  const bf16_t* vq0 = W2T + (size_t)(wave * 32 +      r) * N1;
  const bf16_t* vq1 = W2T + (size_t)(wave * 32 + 16 + r) * N1;
  for (int kk = 0; kk < 8; ++kk) {
    int k0 = kk * 32 + q * 8;
    int co = (k0 << 1) ^ rs8;
    bf16x8_t a0 = *(const bf16x8_t*)(smem + ((     r) << 9) + co);
    bf16x8_t a1 = *(const bf16x8_t*)(smem + ((16 + r) << 9) + co);
    bf16x8_t bb0 = *(const bf16x8_t*)(vq0 + k0);
    bf16x8_t bb1 = *(const bf16x8_t*)(vq1 + k0);
    acc2[0][0] = __builtin_amdgcn_mfma_f32_16x16x32_bf16(a0, bb0, acc2[0][0], 0, 0, 0);
    acc2[1][0] = __builtin_amdgcn_mfma_f32_16x16x32_bf16(a1, bb0, acc2[1][0], 0, 0, 0);
    acc2[0][1] = __builtin_amdgcn_mfma_f32_16x16x32_bf16(a0, bb1, acc2[0][1], 0, 0, 0);
    acc2[1][1] = __builtin_amdgcn_mfma_f32_16x16x32_bf16(a1, bb1, acc2[1][1], 0, 0, 0);
  }
#pragma unroll
  for (int mt = 0; mt < 2; ++mt) {
#pragma unroll
    for (int ct = 0; ct < 2; ++ct) {
      int cc = wave * 32 + ct * 16 + r;
      float bias = b2[cc];
#pragma unroll
      for (int reg = 0; reg < 4; ++reg) {
        int m = mt * 16 + q * 4 + reg;
        out[(bN + m) * N2 + cc] = fmaxf(acc2[mt][ct][reg] + bias, 0.0f);
      }
    }
  }
}

// ----------------------------------------------------------------- launch --
extern "C" void kernel_launch(void* const* d_in, const int* in_sizes, int n_in,
                              void* d_out, int out_size, void* d_ws, size_t ws_size,
                              hipStream_t stream) {
  (void)in_sizes; (void)n_in; (void)out_size; (void)ws_size;
  const float* xyz1    = (const float*)d_in[0];
  const float* xyz2    = (const float*)d_in[1];
  const float* points1 = (const float*)d_in[2];
  const float* points2 = (const float*)d_in[3];
  const float* W1      = (const float*)d_in[4];
  const float* b1      = (const float*)d_in[5];
  const float* W2      = (const float*)d_in[6];
  const float* b2      = (const float*)d_in[7];
  float* out = (float*)d_out;
  char* ws = (char*)d_ws;
  bf16_t* W1T   = (bf16_t*)(ws + WS_W1T);
  bf16_t* W2T   = (bf16_t*)(ws + WS_W2T);
  float4* xyz2p = (float4*)(ws + WS_XYZ2P);

  prep_kernel<<<576, 256, 0, stream>>>(W1, W2, xyz2, W1T, W2T, xyz2p);
  fp_fused_kernel<<<2048, 256, 0, stream>>>(xyz1, xyz2p, points1, points2,
                                            W1T, b1, W2T, b2, out);
}

// Round 2
// 194.586 us; speedup vs baseline: 1.3041x; 1.3041x over previous
//
// PointNet++ FP: three_nn + three_interpolate + pointwise MLP(384->256->128)
// Round 10: scalar scan + high occupancy (r9 post-mortem: vector-load scan
// killed per-wave efficiency; r8's s_load ping-pong is the right scan, it just
// needs more waves). Structure: 1024 blocks x 512 thr (8 waves), block owns 64
// points; wave w scans candidate chunk [w*256, w*256+256) with WAVE-UNIFORM
// addresses (lane=point) -> compiler emits s_load ping-pong, scan is pure
// SGPR-fed VALU. 48KB LDS -> 3 blocks/CU = 24 waves/CU (75%) vs r8's 12.
//  * cross-chunk fold: ALL lanes redundantly fold their point's 8 partials
//    from LDS (float4/int4) -> no wave0 serialization, no iw arrays.
//  * gather stages BOTH interp (cols 0..255) and points1 skip (cols 256..383)
//    into Xs[64][384] bf16, XOR-swizzled (byte^=(row&7)<<4) -> layer-1 is one
//    12-step K-loop, conflict-free ds_read_b128.
//  * Y1[64][256] overlays Xs (barrier-fenced); layer-2 as r9.
// 5 barriers: scan->fold->gather->L1->Y1->L2.
// MFMA 16x16x32 bf16 layouts (learn_hip m89/m120 verified):
//   A: [m=lane&15][k=(lane>>4)*8+j]   B: [k=(lane>>4)*8+j][n=lane&15]
//   D: [row=(lane>>4)*4+reg][col=lane&15]
#include <hip/hip_runtime.h>

typedef __bf16 bf16_t;
typedef bf16_t bf16x2_t __attribute__((ext_vector_type(2)));
typedef bf16_t bf16x4_t __attribute__((ext_vector_type(4)));
typedef bf16_t bf16x8_t __attribute__((ext_vector_type(8)));
typedef float floatx4_t __attribute__((ext_vector_type(4)));

constexpr int B_ = 8, N_ = 8192, M_ = 2048;
constexpr int C1 = 128, C2 = 256;
constexpr int K1 = 384, N1 = 256, N2 = 128;

// ws layout (bytes) -- unchanged
constexpr size_t WS_W1T   = 0;         // bf16  [256][384]  = 196608 B
constexpr size_t WS_W2T   = 196608;    // bf16  [128][256]  =  65536 B
constexpr size_t WS_XYZ2P = 262144;    // float4[8*2048]    = 262144 B

// ---------------------------------------------------------------- prep ----
__global__ __launch_bounds__(256) void prep_kernel(
    const float* __restrict__ W1, const float* __restrict__ W2,
    const float* __restrict__ xyz2,
    bf16_t* __restrict__ W1T, bf16_t* __restrict__ W2T,
    float4* __restrict__ xyz2p) {
  int bid = blockIdx.x, tid = threadIdx.x;
  if (bid < 384) {                       // W1 [384][256] -> W1T [256][384]
    int t = bid * 256 + tid;             // 98304 elems
    int n = t / K1, k = t - n * K1;
    W1T[t] = (bf16_t)W1[k * N1 + n];
  } else if (bid < 512) {                // W2 [256][128] -> W2T [128][256]
    int t = (bid - 384) * 256 + tid;     // 32768 elems
    int n = t / N1, k = t - n * N1;
    W2T[t] = (bf16_t)W2[k * N2 + n];
  } else {                               // xyz2 -> float4{x,y,z,|q|^2}
    int t = (bid - 512) * 256 + tid;     // 16384 elems
    const float* p = xyz2 + (size_t)t * 3;
    float x = p[0], y = p[1], z = p[2];
    xyz2p[t] = make_float4(x, y, z, x * x + y * y + z * z);
  }
}

// ---------------------------------------------- fused nn+interp+MLP -------
// 1024 blocks x 512 threads; block owns 64 points of batch b = bi&7 (XCD-local
// points2/xyz2p in that XCD's L2). Wave w = candidate chunk of 256.
__global__ __launch_bounds__(512, 6) void fp_fused_kernel(
    const float* __restrict__ xyz1, const float4* __restrict__ xyz2p,
    const float* __restrict__ points1, const float* __restrict__ points2,
    const bf16_t* __restrict__ W1T, const float* __restrict__ b1,
    const bf16_t* __restrict__ W2T, const float* __restrict__ b2,
    float* __restrict__ out) {
  // Xs [64][384] bf16 swizzled (48KB); sd/si [8][64] float4/int4 overlay the
  // first 16KB during the scan; Y1 [64][256] bf16 overlays after layer 1.
  __shared__ __align__(16) char smem[64 * 768];   // 49152 B

  int bi = blockIdx.x;
  int b = bi & 7;                  // batch -> XCD (round-robin)
  int base = (bi >> 3) * 64;       // tile within batch (0..127)
  int tid = threadIdx.x;
  int wave = __builtin_amdgcn_readfirstlane(tid >> 6);  // 0..7
  int lane = tid & 63;
  size_t bN = (size_t)b * N_ + base;

  float4* sdv = (float4*)smem;             // [8][64] biased top-3 dists
  int4*   siv = (int4*)(smem + 8192);      // [8][64] top-3 indices

  float w0, w1, w2;                // blend weights (lane = point)
  int   i0, i1, i2;                // top-3 indices (lane = point)

  // ===== Phase S: three_nn. wave=chunk of 256 cands, lane=point (uniform
  // candidate addresses -> s_load ping-pong; SGPR-fed VALU). ================
  {
    const float* p1 = xyz1 + (bN + lane) * 3;
    float x = p1[0], y = p1[1], z = p1[2];
    float sq1 = x * x + y * y + z * z;
    float m2x = -2.0f * x, m2y = -2.0f * y, m2z = -2.0f * z;

    const float4* p2 = xyz2p + b * M_ + (wave << 8);  // wave-uniform base
    int jb = wave << 8;

    float cd0[4], cd1[4], cd2[4];
    int   ci0[4], ci1[4], ci2[4];
#pragma unroll
    for (int t = 0; t < 4; ++t) {
      cd0[t] = 1e30f; cd1[t] = 1e30f; cd2[t] = 1e30f;
      ci0[t] = 0; ci1[t] = 0; ci2[t] = 0;
    }
    // top-3 insert on d_rel = d2 - sq1 (per-point constant shift, same argmin)
    auto proc = [&](const float4& qv, int jj) {
      int tc = jj & 3;                       // chain id (const after unroll)
      float d = fmaf(m2x, qv.x, fmaf(m2y, qv.y, fmaf(m2z, qv.z, qv.w)));
      bool l0 = d < cd0[tc], l1 = d < cd1[tc], l2 = d < cd2[tc];
      float n0v = fminf(cd0[tc], d);
      float n1v = __builtin_amdgcn_fmed3f(d, cd0[tc], cd1[tc]);
      float n2v = __builtin_amdgcn_fmed3f(d, cd1[tc], cd2[tc]);
      int t1 = l0 ? ci0[tc] : jj;            // carry into slot1
      int t2 = l1 ? ci1[tc] : jj;            // carry into slot2
      ci0[tc] = l0 ? jj : ci0[tc];
      ci1[tc] = l1 ? t1 : ci1[tc];
      ci2[tc] = l2 ? t2 : ci2[tc];
      cd0[tc] = n0v; cd1[tc] = n1v; cd2[tc] = n2v;
    };

    float4 bA[8], bB[8];
#pragma unroll
    for (int t = 0; t < 8; ++t) bA[t] = p2[t];
    for (int j = 0; j < 256; j += 16) {
#pragma unroll
      for (int t = 0; t < 8; ++t) bB[t] = p2[j + 8 + t];
#pragma unroll
      for (int t = 0; t < 8; ++t) proc(bA[t], jb + j + t);
      if (j + 16 < 256) {
#pragma unroll
        for (int t = 0; t < 8; ++t) bA[t] = p2[j + 16 + t];
      }
#pragma unroll
      for (int t = 0; t < 8; ++t) proc(bB[t], jb + j + 8 + t);
    }

    // merge the 4 chains -> sorted s0<=s1<=s2
    float s0 = cd0[0], s1 = cd1[0], s2 = cd2[0];
    int   a0 = ci0[0], a1 = ci1[0], a2 = ci2[0];
    auto ins = [&](float d, int j) {
      if (d < s2) {
        if (d < s1) {
          s2 = s1; a2 = a1;
          if (d < s0) { s1 = s0; a1 = a0; s0 = d; a0 = j; }
          else        { s1 = d;  a1 = j; }
        } else { s2 = d; a2 = j; }
      }
    };
#pragma unroll
    for (int t = 1; t < 4; ++t) {
      ins(cd0[t], ci0[t]); ins(cd1[t], ci1[t]); ins(cd2[t], ci2[t]);
    }
    sdv[wave * 64 + lane] = make_float4(s0 + sq1, s1 + sq1, s2 + sq1, 0.0f);
    siv[wave * 64 + lane] = make_int4(a0, a1, a2, 0);
  }
  __syncthreads();

  // ===== Fold: every lane folds its point's 8 chunk-partials (redundant
  // across waves -> no serialization, results live in regs of lane=point). ===
  {
    float4 d0 = sdv[lane];  int4 x0 = siv[lane];
    float t0 = d0.x, t1 = d0.y, t2 = d0.z;
    int   a0 = x0.x, a1 = x0.y, a2 = x0.z;
    auto ins = [&](float d, int j) {
      if (d < t2) {
        if (d < t1) {
          t2 = t1; a2 = a1;
          if (d < t0) { t1 = t0; a1 = a0; t0 = d; a0 = j; }
          else        { t1 = d;  a1 = j; }
        } else { t2 = d; a2 = j; }
      }
    };
#pragma unroll
    for (int c = 1; c < 8; ++c) {
      float4 dd = sdv[c * 64 + lane];  int4 xx = siv[c * 64 + lane];
      ins(dd.x, xx.x); ins(dd.y, xx.y); ins(dd.z, xx.z);
    }
    float e0 = fmaxf(t0, 1e-10f), e1 = fmaxf(t1, 1e-10f), e2 = fmaxf(t2, 1e-10f);
    float r0 = 1.0f / e0, r1 = 1.0f / e1, r2 = 1.0f / e2;
    float rs = 1.0f / (r0 + r1 + r2);
    w0 = r0 * rs; w1 = r1 * rs; w2 = r2 * rs;
    i0 = a0; i1 = a1; i2 = a2;
  }
  __syncthreads();   // sd/si region about to be overwritten by Xs

  // ===== Phase A: gather -> Xs[64][384] bf16 swizzled ======================
  // wave w fills rows w*8..w*8+7 (interp cols 0..255 + skip cols 256..383).
#pragma unroll 2
  for (int i = 0; i < 8; ++i) {
    int p = wave * 8 + i;
    int j0 = __shfl(i0, p), j1 = __shfl(i1, p), j2 = __shfl(i2, p);
    float u0 = __shfl(w0, p), u1 = __shfl(w1, p), u2 = __shfl(w2, p);
    const float* g0 = points2 + ((size_t)b * M_ + j0) * C2 + lane * 4;
    const float* g1 = points2 + ((size_t)b * M_ + j1) * C2 + lane * 4;
    const float* g2 = points2 + ((size_t)b * M_ + j2) * C2 + lane * 4;
    float4 a0 = *(const float4*)g0;
    float4 a1 = *(const float4*)g1;
    float4 a2 = *(const float4*)g2;
    bf16x4_t v;
    v[0] = (bf16_t)(u0 * a0.x + u1 * a1.x + u2 * a2.x);
    v[1] = (bf16_t)(u0 * a0.y + u1 * a1.y + u2 * a2.y);
    v[2] = (bf16_t)(u0 * a0.z + u1 * a1.z + u2 * a2.z);
    v[3] = (bf16_t)(u0 * a0.w + u1 * a1.w + u2 * a2.w);
    int off = p * 768 + ((lane * 8) ^ (i << 4));      // (p&7)==i
    *(bf16x4_t*)(smem + off) = v;
    const float* pp1 = points1 + (bN + p) * C1 + lane * 2;
    float2 s = *(const float2*)pp1;
    bf16x2_t v2; v2[0] = (bf16_t)s.x; v2[1] = (bf16_t)s.y;
    int off2 = p * 768 + ((512 + lane * 4) ^ (i << 4));
    *(bf16x2_t*)(smem + off2) = v2;
  }
  __syncthreads();

  int q = lane >> 4, r = lane & 15;
  int rs8 = (r & 7) << 4;            // row-swizzle XOR (rows r,16+r,32+r,48+r)

  // ---- Layer 1: [64 x 384] x [384 x 256] -> Y1, wave owns 32 cols
  floatx4_t acc[4][2] = {};
  int cw = wave * 32;
  const bf16_t* wq0 = W1T + (size_t)(cw +      r) * K1;
  const bf16_t* wq1 = W1T + (size_t)(cw + 16 + r) * K1;
  for (int kk = 0; kk < 12; ++kk) {
    int k0 = kk * 32 + q * 8;
    int co = (k0 << 1) ^ rs8;
    bf16x8_t a0 = *(const bf16x8_t*)(smem + (     r) * 768 + co);
    bf16x8_t a1 = *(const bf16x8_t*)(smem + (16 + r) * 768 + co);
    bf16x8_t a2 = *(const bf16x8_t*)(smem + (32 + r) * 768 + co);
    bf16x8_t a3 = *(const bf16x8_t*)(smem + (48 + r) * 768 + co);
    bf16x8_t bb0 = *(const bf16x8_t*)(wq0 + k0);
    bf16x8_t bb1 = *(const bf16x8_t*)(wq1 + k0);
    acc[0][0] = __builtin_amdgcn_mfma_f32_16x16x32_bf16(a0, bb0, acc[0][0], 0, 0, 0);
    acc[1][0] = __builtin_amdgcn_mfma_f32_16x16x32_bf16(a1, bb0, acc[1][0], 0, 0, 0);
    acc[2][0] = __builtin_amdgcn_mfma_f32_16x16x32_bf16(a2, bb0, acc[2][0], 0, 0, 0);
    acc[3][0] = __builtin_amdgcn_mfma_f32_16x16x32_bf16(a3, bb0, acc[3][0], 0, 0, 0);
    acc[0][1] = __builtin_amdgcn_mfma_f32_16x16x32_bf16(a0, bb1, acc[0][1], 0, 0, 0);
    acc[1][1] = __builtin_amdgcn_mfma_f32_16x16x32_bf16(a1, bb1, acc[1][1], 0, 0, 0);
    acc[2][1] = __builtin_amdgcn_mfma_f32_16x16x32_bf16(a2, bb1, acc[2][1], 0, 0, 0);
    acc[3][1] = __builtin_amdgcn_mfma_f32_16x16x32_bf16(a3, bb1, acc[3][1], 0, 0, 0);
  }
  __syncthreads();   // Xs dead only when ALL waves finished layer-1 LDS reads

  // bias + relu -> Y1 [64][256] bf16 (overlays Xs, 512B rows, same swizzle)
#pragma unroll
  for (int ct = 0; ct < 2; ++ct) {
    int nn = cw + ct * 16 + r;
    float bias = b1[nn];
#pragma unroll
    for (int mt = 0; mt < 4; ++mt) {
#pragma unroll
      for (int reg = 0; reg < 4; ++reg) {
        int m = mt * 16 + q * 4 + reg;
        int off = (m << 9) + ((nn << 1) ^ ((m & 7) << 4));
        *(bf16_t*)(smem + off) = (bf16_t)fmaxf(acc[mt][ct][reg] + bias, 0.0f);
      }
    }
  }
  __syncthreads();

  // ---- Layer 2: [64 x 256] x [256 x 128] -> out, wave owns 16 cols
  floatx4_t acc2[4] = {};
  const bf16_t* vq = W2T + (size_t)(wave * 16 + r) * N1;
  for (int kk = 0; kk < 8; ++kk) {
    int k0 = kk * 32 + q * 8;
    int co = (k0 << 1) ^ rs8;
    bf16x8_t a0 = *(const bf16x8_t*)(smem + ((     r) << 9) + co);
    bf16x8_t a1 = *(const bf16x8_t*)(smem + ((16 + r) << 9) + co);
    bf16x8_t a2 = *(const bf16x8_t*)(smem + ((32 + r) << 9) + co);
    bf16x8_t a3 = *(const bf16x8_t*)(smem + ((48 + r) << 9) + co);
    bf16x8_t bb = *(const bf16x8_t*)(vq + k0);
    acc2[0] = __builtin_amdgcn_mfma_f32_16x16x32_bf16(a0, bb, acc2[0], 0, 0, 0);
    acc2[1] = __builtin_amdgcn_mfma_f32_16x16x32_bf16(a1, bb, acc2[1], 0, 0, 0);
    acc2[2] = __builtin_amdgcn_mfma_f32_16x16x32_bf16(a2, bb, acc2[2], 0, 0, 0);
    acc2[3] = __builtin_amdgcn_mfma_f32_16x16x32_bf16(a3, bb, acc2[3], 0, 0, 0);
  }
  {
    int cc = wave * 16 + r;
    float bias = b2[cc];
#pragma unroll
    for (int mt = 0; mt < 4; ++mt) {
#pragma unroll
      for (int reg = 0; reg < 4; ++reg) {
        int m = mt * 16 + q * 4 + reg;
        out[(bN + m) * N2 + cc] = fmaxf(acc2[mt][reg] + bias, 0.0f);
      }
    }
  }
}

// ----------------------------------------------------------------- launch --
extern "C" void kernel_launch(void* const* d_in, const int* in_sizes, int n_in,
                              void* d_out, int out_size, void* d_ws, size_t ws_size,
                              hipStream_t stream) {
  (void)in_sizes; (void)n_in; (void)out_size; (void)ws_size;
  const float* xyz1    = (const float*)d_in[0];
  const float* xyz2    = (const float*)d_in[1];
  const float* points1 = (const float*)d_in[2];
  const float* points2 = (const float*)d_in[3];
  const float* W1      = (const float*)d_in[4];
  const float* b1      = (const float*)d_in[5];
  const float* W2      = (const float*)d_in[6];
  const float* b2      = (const float*)d_in[7];
  float* out = (float*)d_out;
  char* ws = (char*)d_ws;
  bf16_t* W1T   = (bf16_t*)(ws + WS_W1T);
  bf16_t* W2T   = (bf16_t*)(ws + WS_W2T);
  float4* xyz2p = (float4*)(ws + WS_XYZ2P);

  prep_kernel<<<576, 256, 0, stream>>>(W1, W2, xyz2, W1T, W2T, xyz2p);
  fp_fused_kernel<<<1024, 512, 0, stream>>>(xyz1, xyz2p, points1, points2,
                                            W1T, b1, W2T, b2, out);
}